// Round 10
// baseline (357.462 us; speedup 1.0000x reference)
//
#include <hip/hip_runtime.h>
#include <hip/hip_bf16.h>
#include <stdint.h>

// Problem: b=32, s=256, h=1024, 5 options.
// out = 0.5 * sum_n V_n @ o_n,  V_n = sum_{i!=n} softmax_k(q_i . o_k)_n,  q_i = o_i @ W
// bias is softmax-shift-invariant -> ignored.
// Round 10: gram was LDS-BW-bound (60KB/block-step vs 97cyc MFMA). O operand
// now loaded DIRECT global->reg (per-lane dwordx4, L2-resident) -- LDS traffic
// halves to 30KB. Q staged in BK=64 super-steps (5 uniform DMA/thread), 3-buf,
// one barrier/super-step; compiler manages O-reg vmcnt waits.

#define BB 32
#define SS 256
#define HH 1024

typedef __attribute__((ext_vector_type(4))) float f32x4;
typedef __attribute__((ext_vector_type(8))) __bf16 bf16x8;
typedef __attribute__((ext_vector_type(4))) __bf16 bf16x4;

__device__ constexpr int PAIR(int i, int n) { return i * 4 + (n > i ? n - 1 : n); }

__device__ __forceinline__ void gload_lds16(const void* g, void* l) {
  __builtin_amdgcn_global_load_lds((const __attribute__((address_space(1))) void*)g,
                                   (__attribute__((address_space(3))) void*)l, 16, 0, 0);
}

__global__ void canary(float* out, float v) { out[0] = v; }

// ---------------------------------------------------------------------------
// fp32 -> bf16 flat cast of the 5 options into Obf[m][b][s][h].
__global__ __launch_bounds__(256) void cast_all(
    const float* p0, const float* p1, const float* p2, const float* p3, const float* p4,
    __bf16* __restrict__ dst)
{
  int m = blockIdx.x >> 12;
  long off = ((long)(blockIdx.x & 4095) * 256 + threadIdx.x) * 8;
  const float* src = m == 0 ? p0 : m == 1 ? p1 : m == 2 ? p2 : m == 3 ? p3 : p4;
  float4 v0 = *(const float4*)(src + off);
  float4 v1 = *(const float4*)(src + off + 4);
  bf16x8 h;
  h[0] = (__bf16)v0.x; h[1] = (__bf16)v0.y; h[2] = (__bf16)v0.z; h[3] = (__bf16)v0.w;
  h[4] = (__bf16)v1.x; h[5] = (__bf16)v1.y; h[6] = (__bf16)v1.z; h[7] = (__bf16)v1.w;
  *(bf16x8*)(dst + (long)m * BB * SS * HH + off) = h;
}

// ---------------------------------------------------------------------------
// W (1024x1024 fp32) -> Wt (bf16, transposed). 64x64 tiles, grid 256.
__global__ __launch_bounds__(256) void cast_trW(const float* __restrict__ src,
                                                __bf16* __restrict__ dstT)
{
  __shared__ __bf16 tile[64][72];
  int ct = blockIdx.x & 15, rt = blockIdx.x >> 4;
  const float* s = src + (long)(rt * 64) * 1024 + ct * 64;
  int t = threadIdx.x;
#pragma unroll
  for (int p = 0; p < 4; p++) {
    int c = t + p * 256;
    int row = c >> 4, c4 = c & 15;
    float4 v = *(const float4*)(s + (long)row * 1024 + c4 * 4);
    bf16x4 h;
    h[0] = (__bf16)v.x; h[1] = (__bf16)v.y; h[2] = (__bf16)v.z; h[3] = (__bf16)v.w;
    *(bf16x4*)&tile[row][c4 * 4] = h;
  }
  __syncthreads();
#pragma unroll
  for (int p = 0; p < 4; p++) {
    int c = t + p * 256;
    int hr = c >> 4, s4 = c & 15;
    bf16x4 h;
    h[0] = tile[s4 * 4 + 0][hr];
    h[1] = tile[s4 * 4 + 1][hr];
    h[2] = tile[s4 * 4 + 2][hr];
    h[3] = tile[s4 * 4 + 3][hr];
    *(bf16x4*)(dstT + (long)(ct * 64 + hr) * 1024 + rt * 64 + s4 * 4) = h;
  }
}

// ---------------------------------------------------------------------------
// qgemm: Q = Obf @ Wt. 128x128 tile, BK=32, XCD/L2 remap (grid 2560),
// 3-buffer counted-vmcnt pipeline + XOR swizzle (both sides) + setprio.
__global__ __launch_bounds__(256, 3) void qgemm_b16(
    const __bf16* __restrict__ A, const __bf16* __restrict__ Bt, __bf16* __restrict__ C)
{
  __shared__ __align__(16) char ldsb[3 * 16384];  // 48 KB: per buf A[8K] B[8K]
  int lin = blockIdx.x;
  int xcd = lin & 7, idx = lin >> 3;
  int rt = xcd * 40 + (idx >> 3), ct = idx & 7;
  int t = threadIdx.x, l = t & 63, w = t >> 6;
  int wm = w >> 1, wn = w & 1;
  f32x4 acc[4][4] = {};

  const char *gA0, *gA1, *gB0, *gB1;
  {
    int c0 = t, c1 = t + 256;
    int r0 = c0 >> 2, h0 = (c0 & 3) ^ ((c0 >> 3) & 3);
    int r1 = c1 >> 2, h1 = (c1 & 3) ^ ((c1 >> 3) & 3);
    gA0 = (const char*)(A + (long)(rt * 128 + r0) * 1024 + h0 * 8);
    gA1 = (const char*)(A + (long)(rt * 128 + r1) * 1024 + h1 * 8);
    gB0 = (const char*)(Bt + (long)(ct * 128 + r0) * 1024 + h0 * 8);
    gB1 = (const char*)(Bt + (long)(ct * 128 + r1) * 1024 + h1 * 8);
  }
  int dst0 = w * 1024, dst1 = (w + 4) * 1024;

#define STAGE(BUF)                                                \
  {                                                               \
    char* base = ldsb + (BUF) * 16384;                            \
    gload_lds16(gA0, base + dst0); gA0 += 64;                     \
    gload_lds16(gA1, base + dst1); gA1 += 64;                     \
    gload_lds16(gB0, base + 8192 + dst0); gB0 += 64;              \
    gload_lds16(gB1, base + 8192 + dst1); gB1 += 64;              \
  }

  int lr = l & 15, sl = l >> 4;
  int swz = (sl ^ ((lr >> 1) & 3)) * 16;
  int aoff = (wm * 64 + lr) * 64 + swz;
  int boff = 8192 + (wn * 64 + lr) * 64 + swz;

#define COMPUTE(BUF)                                                                   \
  {                                                                                    \
    const char* base = ldsb + (BUF) * 16384;                                           \
    bf16x8 af[4], bfr[4];                                                              \
    _Pragma("unroll") for (int i = 0; i < 4; i++) {                                    \
      af[i]  = *(const bf16x8*)(base + aoff + i * 1024);                               \
      bfr[i] = *(const bf16x8*)(base + boff + i * 1024);                               \
    }                                                                                  \
    __builtin_amdgcn_s_setprio(1);                                                     \
    _Pragma("unroll") for (int i = 0; i < 4; i++)                                      \
      _Pragma("unroll") for (int j = 0; j < 4; j++)                                    \
        acc[i][j] = __builtin_amdgcn_mfma_f32_16x16x32_bf16(af[i], bfr[j],             \
                                                            acc[i][j], 0, 0, 0);       \
    __builtin_amdgcn_s_setprio(0);                                                     \
  }

#define STEP(CUR, STG)                                          \
  asm volatile("s_waitcnt vmcnt(4)" ::: "memory");              \
  __builtin_amdgcn_s_barrier();                                 \
  STAGE(STG);                                                   \
  COMPUTE(CUR);

  STAGE(0)
  STAGE(1)
  for (int it = 0; it < 10; it++) {
    STEP(0, 2)
    STEP(1, 0)
    STEP(2, 1)
  }
  asm volatile("s_waitcnt vmcnt(4)" ::: "memory");
  __builtin_amdgcn_s_barrier();
  COMPUTE(0)
  asm volatile("s_waitcnt vmcnt(0)" ::: "memory");
  __builtin_amdgcn_s_barrier();
  COMPUTE(1)
#undef STEP
#undef COMPUTE
#undef STAGE

#pragma unroll
  for (int i = 0; i < 4; i++) {
    long mrow = (long)rt * 128 + wm * 64 + i * 16 + ((l >> 4) << 2);
#pragma unroll
    for (int j = 0; j < 4; j++) {
      int n = ct * 128 + wn * 64 + j * 16 + (l & 15);
#pragma unroll
      for (int r = 0; r < 4; r++)
        C[(mrow + r) * 1024 + n] = (__bf16)acc[i][j][r];
    }
  }
}

// ---------------------------------------------------------------------------
// gram: 20 cross-grams + lane-local softmax -> V.
// Round 10 structure: 16 super-steps (BK=64). Per super-step:
//   vmcnt(10) + barrier (Q-buffer protocol) -> load O-hi (global->reg) ->
//   stage Q(ss+2) (5 uniform DMA/thread) -> dsread Q-lo + 20 MFMA(oLo) ->
//   load O-lo(ss+1) -> dsread Q-hi + 20 MFMA(oHi).
// O never touches LDS. Compiler inserts counted vmcnt for O-reg uses, which
// transitively drains Qstage(ss) before the barrier (traced r10 analysis).
__global__ __launch_bounds__(256, 2) void gram_b16(
    const __bf16* __restrict__ Q, const __bf16* __restrict__ O, __bf16* __restrict__ V)
{
  __shared__ __align__(16) char ldsb[3 * 20480];  // 3 x (5 opts x 32 rows x 64 k)
  int bid = blockIdx.x;
  int xcd = bid & 7, idx = bid >> 3;          // 2048 = 8 XCD x 256 (bijective)
  int b = xcd * 4 + (idx >> 6);               // 4 batches per XCD
  int rem = idx & 63;
  int s1t = rem >> 3, s2t = rem & 7;          // s1t-major within batch
  int t = threadIdx.x, l = t & 63, w = t >> 6;
  int pr = w >> 1, pc = w & 1;
  f32x4 acc[20] = {};

  long qrow0 = (long)b * SS + s1t * 32;
  long orow0 = (long)b * SS + s2t * 32;
  int slog = (l & 3) ^ ((l >> 3) & 3);  // pre-swizzled k-slot for staging

  // Q staging: wave w stages chunks g = w + 4p (p = option). Chunk g:
  // option g>>2, row-block (g&3)>>1, k-half (g&3)&1. Lane l: row l>>2,
  // k-slot slog. LDS dst = g*1024 + l*16 (linear, wave-uniform base).
  const char* qp[5];
  int qdst[5];
#pragma unroll
  for (int p = 0; p < 5; p++) {
    long row = qrow0 + (long)p * (BB * SS) + (w >> 1) * 16 + (l >> 2);
    qp[p] = (const char*)(Q + row * HH + (w & 1) * 32 + slog * 8);
    qdst[p] = (w + 4 * p) * 1024;
  }

  // O-direct: frag m = rows orow0+pc*16+lr, 16B at k0 + half*32 + sl*8.
  int lr = l & 15, sl = l >> 4;
  const char* op[5];
#pragma unroll
  for (int m = 0; m < 5; m++) {
    long row = orow0 + (long)m * (BB * SS) + pc * 16 + lr;
    op[m] = (const char*)(O + row * HH + sl * 8);
  }

  int swz = (sl ^ ((lr >> 1) & 3)) * 16;
  int qsub = pr * 2;  // chunk sub-index (row-block part)

  bf16x8 qf[5], oLo[5], oHi[5];

#define QSTAGE(BUF)                                                     \
  {                                                                     \
    char* base = ldsb + (BUF) * 20480;                                  \
    _Pragma("unroll") for (int p = 0; p < 5; p++) {                     \
      gload_lds16(qp[p], base + qdst[p]);                               \
      qp[p] += 128;                                                     \
    }                                                                   \
  }

#define LOADQ(BUF, H)                                                             \
  {                                                                               \
    const char* base = ldsb + (BUF) * 20480;                                      \
    _Pragma("unroll") for (int m = 0; m < 5; m++)                                 \
      qf[m] = *(const bf16x8*)(base + (m * 4 + qsub + (H)) * 1024 + lr * 64 + swz); \
  }

#define MFMA20(OF)                                                                     \
  {                                                                                    \
    __builtin_amdgcn_s_setprio(1);                                                     \
    _Pragma("unroll") for (int i = 0; i < 5; i++) {                                    \
      _Pragma("unroll") for (int n = 0; n < 5; n++) {                                  \
        if (n != i)                                                                    \
          acc[PAIR(i, n)] =                                                            \
              __builtin_amdgcn_mfma_f32_16x16x32_bf16(qf[i], OF[n], acc[PAIR(i, n)],   \
                                                      0, 0, 0);                        \
      }                                                                                \
    }                                                                                  \
    __builtin_amdgcn_s_setprio(0);                                                     \
  }

#define OHI_LOAD                                                         \
  _Pragma("unroll") for (int m = 0; m < 5; m++)                          \
      oHi[m] = *(const bf16x8*)(op[m] + 64);

#define OLO_NEXT                                                         \
  _Pragma("unroll") for (int m = 0; m < 5; m++) {                        \
    op[m] += 128;                                                        \
    oLo[m] = *(const bf16x8*)(op[m]);                                    \
  }

#define SUPER(CUR, STG, DOSTAGE, DOLO)                          \
  {                                                             \
    asm volatile("s_waitcnt vmcnt(10)" ::: "memory");           \
    __builtin_amdgcn_s_barrier();                               \
    OHI_LOAD                                                    \
    if (DOSTAGE) { QSTAGE(STG) }                                \
    LOADQ(CUR, 0)                                               \
    MFMA20(oLo)                                                 \
    if (DOLO) { OLO_NEXT }                                      \
    LOADQ(CUR, 1)                                               \
    MFMA20(oHi)                                                 \
  }

  // prologue: stage super-steps 0,1; load O-lo(0)
  QSTAGE(0)
  QSTAGE(1)
#pragma unroll
  for (int m = 0; m < 5; m++) oLo[m] = *(const bf16x8*)(op[m]);

  for (int it = 0; it < 4; it++) {  // ss = 0..11 (stage ss+2 = 2..13)
    SUPER(0, 2, 1, 1)
    SUPER(1, 0, 1, 1)
    SUPER(2, 1, 1, 1)
  }
  SUPER(0, 2, 1, 1)   // ss=12, stage 14
  SUPER(1, 0, 1, 1)   // ss=13, stage 15
  SUPER(2, 0, 0, 1)   // ss=14
  SUPER(0, 0, 0, 0)   // ss=15
#undef SUPER
#undef OLO_NEXT
#undef OHI_LOAD
#undef MFMA20
#undef LOADQ
#undef QSTAGE

  int s1g = s1t * 32 + pr * 16 + ((l >> 4) << 2);
  int s2g = s2t * 32 + pc * 16 + (l & 15);
#pragma unroll
  for (int r = 0; r < 4; r++) {
    float vacc[5] = {0.f, 0.f, 0.f, 0.f, 0.f};
#pragma unroll
    for (int i = 0; i < 5; i++) {
      float gg[5];
      float mx = -3.0e38f;
#pragma unroll
      for (int n = 0; n < 5; n++)
        if (n != i) { gg[n] = acc[PAIR(i, n)][r]; mx = fmaxf(mx, gg[n]); }
      float ee[5], ssum = 0.f;
#pragma unroll
      for (int n = 0; n < 5; n++)
        if (n != i) { ee[n] = __expf(gg[n] - mx); ssum += ee[n]; }
      float inv = 1.0f / ssum;
#pragma unroll
      for (int n = 0; n < 5; n++)
        if (n != i) vacc[n] += ee[n] * inv;
    }
#pragma unroll
    for (int n = 0; n < 5; n++)
      V[((long)(n * 32 + b) * 256 + s1g + r) * 256 + s2g] = (__bf16)vacc[n];
  }
}

// ---------------------------------------------------------------------------
// out = 0.5 * sum_n V_n @ o_n (per batch). A: V rows (bf16, s2-contig).
// B: Obf bf16 (s2 x h), transposed in LDS via 4x4 register sub-blocks.
__global__ __launch_bounds__(256) void pvgemm(
    const __bf16* __restrict__ Vb, const __bf16* __restrict__ Obf, float* __restrict__ out)
{
  __shared__ __bf16 smA[128][40];
  __shared__ __bf16 smB[128][40];
  int bid = blockIdx.x;
  int b = bid >> 4, s1t = (bid >> 3) & 1, ht = bid & 7;
  int t = threadIdx.x, l = t & 63, w = t >> 6;
  int wm = w >> 1, wn = w & 1;
  f32x4 acc[4][4] = {};
#pragma unroll
  for (int n = 0; n < 5; n++) {
    const __bf16* On = Obf + (long)n * BB * SS * HH;
    for (int st2 = 0; st2 < 8; st2++) {
      int s20 = st2 * 32;
#pragma unroll
      for (int p = 0; p < 2; p++) {
        int c = t + p * 256;
        int row = c >> 2, sl = c & 3;
        *(bf16x8*)&smA[row][sl * 8] =
            *(const bf16x8*)(Vb + (long)(n * BB + b) * SS * SS + (long)(s1t * 128 + row) * SS +
                             s20 + sl * 8);
      }
      {
        int h4 = (t & 31) * 4, s2q = (t >> 5) * 4;
        const __bf16* src = On + ((long)b * 256 + s20 + s2q) * 1024 + ht * 128 + h4;
        bf16x4 v0 = *(const bf16x4*)(src);
        bf16x4 v1 = *(const bf16x4*)(src + 1024);
        bf16x4 v2 = *(const bf16x4*)(src + 2048);
        bf16x4 v3 = *(const bf16x4*)(src + 3072);
        bf16x4 c0, c1, c2, c3;
        c0[0] = v0[0]; c0[1] = v1[0]; c0[2] = v2[0]; c0[3] = v3[0];
        c1[0] = v0[1]; c1[1] = v1[1]; c1[2] = v2[1]; c1[3] = v3[1];
        c2[0] = v0[2]; c2[1] = v1[2]; c2[2] = v2[2]; c2[3] = v3[2];
        c3[0] = v0[3]; c3[1] = v1[3]; c3[2] = v2[3]; c3[3] = v3[3];
        *(bf16x4*)&smB[h4 + 0][s2q] = c0;
        *(bf16x4*)&smB[h4 + 1][s2q] = c1;
        *(bf16x4*)&smB[h4 + 2][s2q] = c2;
        *(bf16x4*)&smB[h4 + 3][s2q] = c3;
      }
      __syncthreads();
      bf16x8 af[4], bfr[4];
      int sl = l >> 4, lr = l & 15;
#pragma unroll
      for (int i = 0; i < 4; i++) {
        af[i]  = *(const bf16x8*)&smA[wm * 64 + i * 16 + lr][sl * 8];
        bfr[i] = *(const bf16x8*)&smB[wn * 64 + i * 16 + lr][sl * 8];
      }
#pragma unroll
      for (int i = 0; i < 4; i++)
#pragma unroll
        for (int j = 0; j < 4; j++)
          acc[i][j] = __builtin_amdgcn_mfma_f32_16x16x32_bf16(af[i], bfr[j], acc[i][j], 0, 0, 0);
      __syncthreads();
    }
  }
#pragma unroll
  for (int i = 0; i < 4; i++) {
    int m = s1t * 128 + wm * 64 + i * 16 + ((l >> 4) << 2);
#pragma unroll
    for (int j = 0; j < 4; j++) {
      int n = ht * 128 + wn * 64 + j * 16 + (l & 15);
#pragma unroll
      for (int r = 0; r < 4; r++)
        out[(long)(b * SS + m + r) * HH + n] = 0.5f * acc[i][j][r];
    }
  }
}

// ---------------------------------------------------------------------------
extern "C" void kernel_launch(void* const* d_in, const int* in_sizes, int n_in,
                              void* d_out, int out_size, void* d_ws, size_t ws_size,
                              hipStream_t stream)
{
  const size_t SZ_W = (size_t)HH * HH * 2;           //  2 MB
  const size_t SZ_Q = (size_t)5 * BB * SS * HH * 2;  // 84 MB
  const size_t SZ_V = (size_t)5 * BB * SS * SS * 2;  // 21 MB
  const size_t SZ_O = (size_t)5 * BB * SS * HH * 2;  // 84 MB
  const size_t NEED = SZ_W + SZ_Q + SZ_V + SZ_O;     // 191 MB (proven available r4)
  if (ws_size < NEED) {
    canary<<<1, 1, 0, stream>>>((float*)d_out, (float)(ws_size >> 20));
    return;
  }
  char* ws = (char*)d_ws;
  __bf16* Wt  = (__bf16*)ws;
  __bf16* Qb  = (__bf16*)(ws + SZ_W);
  __bf16* Vb  = (__bf16*)(ws + SZ_W + SZ_Q);
  __bf16* Obf = (__bf16*)(ws + SZ_W + SZ_Q + SZ_V);
  const float* o0 = (const float*)d_in[0];
  const float* o1 = (const float*)d_in[1];
  const float* o2 = (const float*)d_in[2];
  const float* o3 = (const float*)d_in[3];
  const float* o4 = (const float*)d_in[4];

  cast_trW<<<256, 256, 0, stream>>>((const float*)d_in[5], Wt);
  cast_all<<<5 * 4096, 256, 0, stream>>>(o0, o1, o2, o3, o4, Obf);
  qgemm_b16<<<2560, 256, 0, stream>>>(Obf, Wt, Qb);
  gram_b16<<<2048, 256, 0, stream>>>(Qb, Obf, Vb);
  pvgemm<<<512, 256, 0, stream>>>(Vb, Obf, (float*)d_out);
}